// Round 14
// baseline (83.392 us; speedup 1.0000x reference)
//
#include <hip/hip_runtime.h>
#include <hip/hip_bf16.h>

// Problem constants: B=4, N=4096, C=256, H=8 heads, G=4 groups, d=32, n=1024
// M_TOT = B*N = 16384 rows.

typedef __attribute__((ext_vector_type(8))) short bf16x8;  // 8 bf16 (4 VGPRs)
typedef __attribute__((ext_vector_type(4))) float f32x4;

__device__ __forceinline__ unsigned short f2bf(float x){
  __hip_bfloat16 h = __float2bfloat16(x);   // RNE; pairs fuse to v_cvt_pk_bf16_f32
  return __builtin_bit_cast(unsigned short, h);
}

__device__ __forceinline__ bf16x8 cvt8(const float4 f0, const float4 f1){
  bf16x8 v;
  v[0]=(short)f2bf(f0.x); v[1]=(short)f2bf(f0.y);
  v[2]=(short)f2bf(f0.z); v[3]=(short)f2bf(f0.w);
  v[4]=(short)f2bf(f1.x); v[5]=(short)f2bf(f1.y);
  v[6]=(short)f2bf(f1.z); v[7]=(short)f2bf(f1.w);
  return v;
}

// Direct global->LDS copy, 16B/lane. LDS dest is wave-uniform base
// (HW writes lane i at base + i*16); global src is per-lane.
__device__ __forceinline__ void gl_lds16(const unsigned short* g, char* l){
  __builtin_amdgcn_global_load_lds(
      (const __attribute__((address_space(1))) void*)g,
      (__attribute__((address_space(3))) void*)l, 16, 0, 0);
}

// softmax done in exp2 domain: fold SCALE * log2(e) into Q at store time
#define QSCALE (0.17677669529663687f * 1.4426950408889634f)

// Fragment-major layouts (produced by qkv_gemm, consumed by attn):
//  QF[head][qt][lane][e]     : elem = Q[qt*16 + lr][lg*8+e]  (lane = lg*16+lr)
//                              qt stride = 512 elems (16 rows x 32 feats)!
//  KF[head][t][f][lane][e]   : elem = K[32t + perm(lr) + 4f][lg*8+e],
//                              perm(lr) = (lr>>2)*8 + (lr&3)
//  VF[head][t][half][lane][e]: elem = V[32t + lg*8 + e][16*half + lr]
// Strides (elems): head 32768, K/V t 1024, f/half 512, lane 8; Q qt 512.
// attn stages K/V LINEARLY to LDS (lane i <-> byte 16i): conflict-free b128,
// and exactly the global_load_lds wave-uniform-base + lane*16 pattern.
// Q reads are linear 16B/lane.

// ---------------------------------------------------------------------------
// Kernel 1: QKV GEMM (R13 = R12 with the QF qt-stride bug fixed: 512 not
// 1024). 128x128 block tile, BK=32, 8 K-steps, single-buffered; 128B/row
// swizzled LDS; 3 blocks/CU. s = by>>1 (0=Q 1=K 2=V) is BLOCK-uniform.
// Q/K blocks compute D^T via mfma(B,A): fragment rows = features ->
// the 4 acc elems are 4 CONTIGUOUS bf16 features -> every store is one
// aligned ushort4 (was 4 scattered 2B stores). Bit-identical values.
// grid = (128, 6), block = 256.
// ---------------------------------------------------------------------------
__global__ __launch_bounds__(256, 3) void qkv_gemm(
    const float* __restrict__ x, const int* __restrict__ idx,
    const float* __restrict__ w_qkv,
    unsigned short* __restrict__ QF, unsigned short* __restrict__ KF,
    unsigned short* __restrict__ VF)
{
  __shared__ __align__(16) unsigned short Asl[128*64];   // 16 KiB (128B/row)
  __shared__ __align__(16) unsigned short Bsl[128*64];   // 16 KiB
  const int tid = threadIdx.x;
  const int bx = blockIdx.x, by = blockIdx.y;
  const int m0 = bx << 7;
  const int bb = bx >> 5;           // batch (uniform per block)
  const int gg = (bx >> 3) & 3;     // group
  const int j0 = (bx & 31) << 7;    // permuted position base
  const int n0 = by << 7;
  const bool sw = (by < 4);         // Q,K blocks: compute D^T

  int srow[2], brow[2], wb[2];
  #pragma unroll
  for (int it = 0; it < 2; ++it){
    int c = (it << 8) + tid;
    int row = c >> 2;
    int k8 = (c & 3) << 3;
    srow[it] = (bb << 12) + idx[j0 + row];
    brow[it] = n0 + row;
    wb[it] = ((row << 7) + (k8 << 1)) ^ ((row & 7) << 4);   // swizzled byte
  }

  #pragma unroll
  for (int it = 0; it < 2; ++it){
    int k8 = (((it << 8) + tid) & 3) << 3;
    const float* xs = x + srow[it]*256 + k8;
    const float* wsp = w_qkv + brow[it]*256 + k8;
    *(bf16x8*)((char*)Asl + wb[it]) = cvt8(*(const float4*)(xs), *(const float4*)(xs+4));
    *(bf16x8*)((char*)Bsl + wb[it]) = cvt8(*(const float4*)(wsp), *(const float4*)(wsp+4));
  }
  __syncthreads();

  const int lane = tid & 63;
  const int w = tid >> 6, wr = w >> 1, wc = w & 1;
  const int lr = lane & 15, lg = lane >> 4;
  const int ka = lg << 3;

  f32x4 acc[4][4];
  #pragma unroll
  for (int il = 0; il < 4; ++il)
    #pragma unroll
    for (int jl = 0; jl < 4; ++jl)
      acc[il][jl] = (f32x4){0.f,0.f,0.f,0.f};

  for (int st = 0; st < 8; ++st){
    float4 a0[2], a1[2], c0[2], c1[2];
    const bool pf = (st < 7);
    if (pf){
      int kb = (st + 1) << 5;
      #pragma unroll
      for (int it = 0; it < 2; ++it){
        int k8 = (((it << 8) + tid) & 3) << 3;
        const float* xs = x + srow[it]*256 + kb + k8;
        const float* wsp = w_qkv + brow[it]*256 + kb + k8;
        a0[it] = *(const float4*)(xs);  a1[it] = *(const float4*)(xs + 4);
        c0[it] = *(const float4*)(wsp); c1[it] = *(const float4*)(wsp + 4);
      }
    }

    bf16x8 af[4], bfr[4];
    #pragma unroll
    for (int il = 0; il < 4; ++il){
      int rowA = (wr << 6) + (il << 4) + lr;
      af[il] = *(const bf16x8*)((const char*)Asl + (((rowA << 7) + (ka << 1)) ^ ((rowA & 7) << 4)));
      int rowB = (wc << 6) + (il << 4) + lr;
      bfr[il] = *(const bf16x8*)((const char*)Bsl + (((rowB << 7) + (ka << 1)) ^ ((rowB & 7) << 4)));
    }
    __builtin_amdgcn_s_setprio(1);
    if (sw){
      #pragma unroll
      for (int il = 0; il < 4; ++il)
        #pragma unroll
        for (int jl = 0; jl < 4; ++jl)
          acc[il][jl] = __builtin_amdgcn_mfma_f32_16x16x32_bf16(bfr[jl], af[il], acc[il][jl], 0, 0, 0);
    } else {
      #pragma unroll
      for (int il = 0; il < 4; ++il)
        #pragma unroll
        for (int jl = 0; jl < 4; ++jl)
          acc[il][jl] = __builtin_amdgcn_mfma_f32_16x16x32_bf16(af[il], bfr[jl], acc[il][jl], 0, 0, 0);
    }
    __builtin_amdgcn_s_setprio(0);

    __syncthreads();
    if (pf){
      #pragma unroll
      for (int it = 0; it < 2; ++it){
        *(bf16x8*)((char*)Asl + wb[it]) = cvt8(a0[it], a1[it]);
        *(bf16x8*)((char*)Bsl + wb[it]) = cvt8(c0[it], c1[it]);
      }
      __syncthreads();
    }
  }

  const int s = by >> 1;            // 0=Q 1=K 2=V
  const int hbase = ((bb << 2) + gg) << 3;
  if (s == 2){
    // V path (unswapped): D rows = m, ushort4 via m-contiguity (unchanged)
    #pragma unroll
    for (int il = 0; il < 4; ++il){
      int mr0 = m0 + (wr << 6) + (il << 4) + (lg << 2);
      int nl0 = mr0 & 1023;
      int t   = nl0 >> 5;
      #pragma unroll
      for (int jl = 0; jl < 4; ++jl){
        int ocol = ((by & 1) << 7) + (wc << 6) + (jl << 4) + lr;   // 0..255
        int h  = ocol >> 5, dd = ocol & 31;
        int head = hbase + h;
        int m = nl0 & 31;
        int lane2 = ((m >> 3) << 4) + (dd & 15);
        int half = dd >> 4;
        ushort4 pk;
        pk.x = f2bf(acc[il][jl][0]); pk.y = f2bf(acc[il][jl][1]);
        pk.z = f2bf(acc[il][jl][2]); pk.w = f2bf(acc[il][jl][3]);
        *(ushort4*)(VF + head*32768 + t*1024 + half*512 + lane2*8 + (m & 7)) = pk;
      }
    }
  } else {
    // Q/K path (swapped): acc[il][jl][q] = D[feature fb+q][m-row]
    #pragma unroll
    for (int il = 0; il < 4; ++il){
      int m  = m0 + (wr << 6) + (il << 4) + lr;
      int nl = m & 1023;
      #pragma unroll
      for (int jl = 0; jl < 4; ++jl){
        int fb = ((by & 1) << 7) + (wc << 6) + (jl << 4) + (lg << 2);  // 0..255, mult of 4
        int dd = fb & 31, h = fb >> 5;
        int head = hbase + h;
        ushort4 pk;
        if (s == 0){
          pk.x = f2bf(acc[il][jl][0] * QSCALE); pk.y = f2bf(acc[il][jl][1] * QSCALE);
          pk.z = f2bf(acc[il][jl][2] * QSCALE); pk.w = f2bf(acc[il][jl][3] * QSCALE);
          int qt = nl >> 4, lrq = nl & 15;
          // qt stride = 512 elems (16 rows x 32 feats) -- R12 had 1024 (OOB)
          *(ushort4*)(QF + head*32768 + qt*512 + ((dd >> 3)*16 + lrq)*8 + (dd & 7)) = pk;
        } else {
          pk.x = f2bf(acc[il][jl][0]); pk.y = f2bf(acc[il][jl][1]);
          pk.z = f2bf(acc[il][jl][2]); pk.w = f2bf(acc[il][jl][3]);
          int t = nl >> 5, r0 = nl & 31, f = (r0 >> 2) & 1;
          *(ushort4*)(KF + head*32768 + t*1024 + f*512
                      + (((dd >> 3) << 4) + ((r0 >> 3) << 2) + (r0 & 3))*8 + (dd & 7)) = pk;
        }
      }
    }
  }
}

// ---------------------------------------------------------------------------
// softmax over 16 scores/lane (no max tracking; see R6 analysis). 16 exp2 +
// pack. Denominator accumulated on the matrix pipe (ones-MFMA) by caller.
// ---------------------------------------------------------------------------
__device__ __forceinline__ void softmax16(
    const f32x4 s0, const f32x4 s1, const f32x4 s2, const f32x4 s3,
    bf16x8& pf0, bf16x8& pf1)
{
  float p0=__builtin_amdgcn_exp2f(s0[0]);  float p1=__builtin_amdgcn_exp2f(s0[1]);
  float p2=__builtin_amdgcn_exp2f(s0[2]);  float p3=__builtin_amdgcn_exp2f(s0[3]);
  float p4=__builtin_amdgcn_exp2f(s1[0]);  float p5=__builtin_amdgcn_exp2f(s1[1]);
  float p6=__builtin_amdgcn_exp2f(s1[2]);  float p7=__builtin_amdgcn_exp2f(s1[3]);
  float p8=__builtin_amdgcn_exp2f(s2[0]);  float p9=__builtin_amdgcn_exp2f(s2[1]);
  float p10=__builtin_amdgcn_exp2f(s2[2]); float p11=__builtin_amdgcn_exp2f(s2[3]);
  float p12=__builtin_amdgcn_exp2f(s3[0]); float p13=__builtin_amdgcn_exp2f(s3[1]);
  float p14=__builtin_amdgcn_exp2f(s3[2]); float p15=__builtin_amdgcn_exp2f(s3[3]);

  pf0[0]=(short)f2bf(p0);  pf0[1]=(short)f2bf(p1);
  pf0[2]=(short)f2bf(p2);  pf0[3]=(short)f2bf(p3);
  pf0[4]=(short)f2bf(p4);  pf0[5]=(short)f2bf(p5);
  pf0[6]=(short)f2bf(p6);  pf0[7]=(short)f2bf(p7);
  pf1[0]=(short)f2bf(p8);  pf1[1]=(short)f2bf(p9);
  pf1[2]=(short)f2bf(p10); pf1[3]=(short)f2bf(p11);
  pf1[4]=(short)f2bf(p12); pf1[5]=(short)f2bf(p13);
  pf1[6]=(short)f2bf(p14); pf1[7]=(short)f2bf(p15);
}

// ---------------------------------------------------------------------------
// Kernel 2: attention (R13: Q read uses the corrected 512-elem qt stride).
// 4 waves x 64 q (4 q-groups), dbuf 128-m tiles, global_load_lds staging.
// grid = 512, block = 256.
// ---------------------------------------------------------------------------
__global__ __launch_bounds__(256, 2) void attn_kernel(
    const unsigned short* __restrict__ QF, const unsigned short* __restrict__ KF,
    const unsigned short* __restrict__ VF, unsigned short* __restrict__ OB)
{
  __shared__ __align__(16) char lds[32768];   // [buf 2][K 8KB | V 8KB]
  const int tid  = threadIdx.x;
  const int head = blockIdx.x >> 2;
  const int qblk = blockIdx.x & 3;
  const int lane = tid & 63;
  const int w  = tid >> 6;
  const int lr = lane & 15, lg = lane >> 4;
  const int q0 = qblk * 256 + w * 64;

  const unsigned short* kf = KF + head*32768;
  const unsigned short* vf = VF + head*32768;
  const unsigned short* qbase = QF + head*32768 + (q0 >> 4)*512 + lane*8;

  // prologue: stage tile 0 into buf0 via global_load_lds (wave-uniform dest)
  {
    char* wbase = lds + (w << 10);            // wave's 1KB chunk base
    #pragma unroll
    for (int j = 0; j < 2; ++j){
      const unsigned short* kg = kf + (((j << 8) + tid) << 3);
      const unsigned short* vg = vf + (((j << 8) + tid) << 3);
      gl_lds16(kg, wbase + (j << 12));
      gl_lds16(vg, wbase + 8192 + (j << 12));
    }
  }

  bf16x8 qf[4];
  #pragma unroll
  for (int g = 0; g < 4; ++g)
    qf[g] = *(const bf16x8*)(qbase + g*512);   // linear 16B/lane, 16-row stride

  const short one_bf = (short)0x3F80;   // bf16 1.0
  bf16x8 onesf = {one_bf,one_bf,one_bf,one_bf,one_bf,one_bf,one_bf,one_bf};

  f32x4 o0[4], o1[4], ls[4];
  #pragma unroll
  for (int g = 0; g < 4; ++g){
    o0[g] = (f32x4){0.f,0.f,0.f,0.f};
    o1[g] = (f32x4){0.f,0.f,0.f,0.f};
    ls[g] = (f32x4){0.f,0.f,0.f,0.f};
  }
  const f32x4 zz={0.f,0.f,0.f,0.f};

  __syncthreads();   // drains vmcnt -> tile 0 resident
  int cur = 0;
  for (int it = 0; it < 8; ++it){
    if (it < 7){   // issue next-tile loads straight to the back buffer
      char* db = lds + ((cur^1) << 14) + (w << 10);
      #pragma unroll
      for (int j = 0; j < 2; ++j){
        const unsigned short* kg = kf + (it+1)*4096 + (((j << 8) + tid) << 3);
        const unsigned short* vg = vf + (it+1)*4096 + (((j << 8) + tid) << 3);
        gl_lds16(kg, db + (j << 12));
        gl_lds16(vg, db + 8192 + (j << 12));
      }
    }

    const char* KL = lds + (cur << 14) + lane*16;
    const char* VL = KL + 8192;
    #pragma unroll
    for (int hh = 0; hh < 2; ++hh){
      const char* kp_ = KL + hh*4096;
      const char* vp_ = VL + hh*4096;
      bf16x8 kA0 = *(const bf16x8*)(kp_);
      bf16x8 kB0 = *(const bf16x8*)(kp_ + 1024);
      bf16x8 kA1 = *(const bf16x8*)(kp_ + 2048);
      bf16x8 kB1 = *(const bf16x8*)(kp_ + 3072);
      bf16x8 v00 = *(const bf16x8*)(vp_);
      bf16x8 v01 = *(const bf16x8*)(vp_ + 1024);
      bf16x8 v10 = *(const bf16x8*)(vp_ + 2048);
      bf16x8 v11 = *(const bf16x8*)(vp_ + 3072);

      // 4-group pipeline: QK(g+1) on matrix pipe overlaps softmax(g) VALU.
      __builtin_amdgcn_s_setprio(1);
      f32x4 sA0 = __builtin_amdgcn_mfma_f32_16x16x32_bf16(kA0, qf[0], zz, 0, 0, 0);
      f32x4 sB0 = __builtin_amdgcn_mfma_f32_16x16x32_bf16(kB0, qf[0], zz, 0, 0, 0);
      f32x4 sA1 = __builtin_amdgcn_mfma_f32_16x16x32_bf16(kA1, qf[0], zz, 0, 0, 0);
      f32x4 sB1 = __builtin_amdgcn_mfma_f32_16x16x32_bf16(kB1, qf[0], zz, 0, 0, 0);
      __builtin_amdgcn_s_setprio(0);

      #pragma unroll
      for (int g = 0; g < 4; ++g){
        f32x4 nA0, nB0, nA1, nB1;
        if (g < 3){
          __builtin_amdgcn_s_setprio(1);
          nA0 = __builtin_amdgcn_mfma_f32_16x16x32_bf16(kA0, qf[g+1], zz, 0, 0, 0);
          nB0 = __builtin_amdgcn_mfma_f32_16x16x32_bf16(kB0, qf[g+1], zz, 0, 0, 0);
          nA1 = __builtin_amdgcn_mfma_f32_16x16x32_bf16(kA1, qf[g+1], zz, 0, 0, 0);
          nB1 = __builtin_amdgcn_mfma_f32_16x16x32_bf16(kB1, qf[g+1], zz, 0, 0, 0);
          __builtin_amdgcn_s_setprio(0);
        }
        bf16x8 pf0, pf1;
        softmax16(sA0, sB0, sA1, sB1, pf0, pf1);   // VALU; overlaps QK(g+1)
        __builtin_amdgcn_s_setprio(1);
        o0[g] = __builtin_amdgcn_mfma_f32_16x16x32_bf16(pf0, v00, o0[g], 0, 0, 0);
        o1[g] = __builtin_amdgcn_mfma_f32_16x16x32_bf16(pf0, v01, o1[g], 0, 0, 0);
        o0[g] = __builtin_amdgcn_mfma_f32_16x16x32_bf16(pf1, v10, o0[g], 0, 0, 0);
        o1[g] = __builtin_amdgcn_mfma_f32_16x16x32_bf16(pf1, v11, o1[g], 0, 0, 0);
        ls[g] = __builtin_amdgcn_mfma_f32_16x16x32_bf16(pf0, onesf, ls[g], 0, 0, 0);
        ls[g] = __builtin_amdgcn_mfma_f32_16x16x32_bf16(pf1, onesf, ls[g], 0, 0, 0);
        __builtin_amdgcn_s_setprio(0);
        if (g < 3){ sA0 = nA0; sB0 = nB0; sA1 = nA1; sB1 = nB1; }
      }
    }

    __syncthreads();   // drains vmcnt -> next tile resident; this tile free
    cur ^= 1;
  }

  // epilogue: ls[g][q] holds the full row sum for row q0+g*16+lg*4+q.
  const int bI = head >> 5, gI = (head >> 3) & 3, hI = head & 7;
  unsigned short* obase = OB + (bI*4096 + gI*1024 + q0)*256 + hI*32;
  #pragma unroll
  for (int g = 0; g < 4; ++g){
    #pragma unroll
    for (int q = 0; q < 4; ++q){
      float iv = 1.0f / ls[g][q];
      int r = (g << 4) + (lg << 2) + q;
      obase[r*256 + lr]      = f2bf(o0[g][q] * iv);
      obase[r*256 + 16 + lr] = f2bf(o1[g][q] * iv);
    }
  }
}

// ---------------------------------------------------------------------------
// Kernel 3: projection GEMM (unchanged). A = bf16 OB (cvt-free linear
// staging), B^T = w_proj. out[b, idx[j], :] = row j + bias.
// grid = (256, 2), block = 256.
// ---------------------------------------------------------------------------
__global__ __launch_bounds__(256) void proj_gemm(
    const unsigned short* __restrict__ OB, const float* __restrict__ w_proj,
    const float* __restrict__ b_proj, const int* __restrict__ idx,
    float* __restrict__ out)
{
  __shared__ unsigned short Alds[64*256];
  __shared__ unsigned short Blds[64*256];
  const int tid = threadIdx.x;
  const int m0 = blockIdx.x << 6;
  const int bb = m0 >> 12;

  #pragma unroll
  for (int it = 0; it < 8; ++it){
    int c = (it << 8) + tid;
    int row = c >> 5;
    int k8 = (c & 31) << 3;
    int byt = ((row << 9) + (k8 << 1)) ^ ((row & 7) << 4);
    *(bf16x8*)((char*)Alds + byt) = *(const bf16x8*)(OB + (m0+row)*256 + k8);
  }

  const int w  = tid >> 6, lane = tid & 63;
  const int lr = lane & 15, lg = lane >> 4;
  const int wr = w >> 1,  wc = w & 1;

  for (int nt = 0; nt < 2; ++nt){
    const int n0 = blockIdx.y * 128 + nt * 64;
    __syncthreads();
    #pragma unroll
    for (int it = 0; it < 8; ++it){
      int c = (it << 8) + tid;
      int row = c >> 5;
      int k8 = (c & 31) << 3;
      const float4 f0 = *(const float4*)(w_proj + (n0+row)*256 + k8);
      const float4 f1 = *(const float4*)(w_proj + (n0+row)*256 + k8 + 4);
      bf16x8 v;
      v[0]=(short)f2bf(f0.x); v[1]=(short)f2bf(f0.y);
      v[2]=(short)f2bf(f0.z); v[3]=(short)f2bf(f0.w);
      v[4]=(short)f2bf(f1.x); v[5]=(short)f2bf(f1.y);
      v[6]=(short)f2bf(f1.z); v[7]=(short)f2bf(f1.w);
      int byt = ((row << 9) + (k8 << 1)) ^ ((row & 7) << 4);
      *(bf16x8*)((char*)Blds + byt) = v;
    }
    __syncthreads();

    f32x4 acc[2][2];
    #pragma unroll
    for (int i=0;i<2;++i)
      #pragma unroll
      for (int j=0;j<2;++j)
        acc[i][j] = (f32x4){0.f,0.f,0.f,0.f};

    #pragma unroll
    for (int ks = 0; ks < 8; ++ks){
      bf16x8 af[2], bfr[2];
      int ka = (ks << 5) + (lg << 3);
      #pragma unroll
      for (int i=0;i<2;++i){
        int rowA = (wr << 5) + (i << 4) + lr;
        int bytA = ((rowA << 9) + (ka << 1)) ^ ((rowA & 7) << 4);
        af[i] = *(const bf16x8*)((const char*)Alds + bytA);
        int rowB = (wc << 5) + (i << 4) + lr;
        int bytB = ((rowB << 9) + (ka << 1)) ^ ((rowB & 7) << 4);
        bfr[i] = *(const bf16x8*)((const char*)Blds + bytB);
      }
      #pragma unroll
      for (int i=0;i<2;++i)
        #pragma unroll
        for (int j=0;j<2;++j)
          acc[i][j] = __builtin_amdgcn_mfma_f32_16x16x32_bf16(af[i], bfr[j], acc[i][j], 0, 0, 0);
    }

    #pragma unroll
    for (int i=0;i<2;++i){
      int mr0 = m0 + (wr << 5) + (i << 4) + (lg << 2);
      int rd[4];
      #pragma unroll
      for (int q=0;q<4;++q)
        rd[q] = (bb << 12) + idx[(mr0 + q) & 4095];   // inverse perm as scatter
      #pragma unroll
      for (int j=0;j<2;++j){
        int o = n0 + (wc << 5) + (j << 4) + lr;
        float bias = b_proj[o];
        #pragma unroll
        for (int q=0;q<4;++q)
          out[rd[q]*256 + o] = acc[i][j][q] + bias;
      }
    }
  }
}

// ---------------------------------------------------------------------------
extern "C" void kernel_launch(void* const* d_in, const int* in_sizes, int n_in,
                              void* d_out, int out_size, void* d_ws, size_t ws_size,
                              hipStream_t stream)
{
  const float* x      = (const float*)d_in[0];
  const int*   idx    = (const int*)  d_in[1];
  const float* w_qkv  = (const float*)d_in[2];
  const float* w_proj = (const float*)d_in[3];
  const float* b_proj = (const float*)d_in[4];
  float* out = (float*)d_out;

  char* ws = (char*)d_ws;
  unsigned short* QF = (unsigned short*)(ws);                  // 8 MiB (frag-major)
  unsigned short* KF = (unsigned short*)(ws + (8u  << 20));    // 8 MiB (frag-major)
  unsigned short* VF = (unsigned short*)(ws + (16u << 20));    // 8 MiB (frag-major)
  unsigned short* OB = (unsigned short*)(ws + (24u << 20));    // 8 MiB bf16 O rows

  qkv_gemm<<<dim3(128, 6), 256, 0, stream>>>(x, idx, w_qkv, QF, KF, VF);
  attn_kernel<<<dim3(512), 256, 0, stream>>>(QF, KF, VF, OB);
  proj_gemm<<<dim3(256, 2), 256, 0, stream>>>(OB, w_proj, b_proj, idx, out);
}

// Round 15
// 56.086 us; speedup vs baseline: 1.4869x; 1.4869x over previous
//
#include <hip/hip_runtime.h>
#include <hip/hip_bf16.h>

// Problem constants: B=4, N=4096, C=256, H=8 heads, G=4 groups, d=32, n=1024
// M_TOT = B*N = 16384 rows.

typedef __attribute__((ext_vector_type(8))) short bf16x8;  // 8 bf16 (4 VGPRs)
typedef __attribute__((ext_vector_type(4))) float f32x4;

__device__ __forceinline__ unsigned short f2bf(float x){
  __hip_bfloat16 h = __float2bfloat16(x);   // RNE; pairs fuse to v_cvt_pk_bf16_f32
  return __builtin_bit_cast(unsigned short, h);
}

__device__ __forceinline__ bf16x8 cvt8(const float4 f0, const float4 f1){
  bf16x8 v;
  v[0]=(short)f2bf(f0.x); v[1]=(short)f2bf(f0.y);
  v[2]=(short)f2bf(f0.z); v[3]=(short)f2bf(f0.w);
  v[4]=(short)f2bf(f1.x); v[5]=(short)f2bf(f1.y);
  v[6]=(short)f2bf(f1.z); v[7]=(short)f2bf(f1.w);
  return v;
}

// softmax done in exp2 domain: fold SCALE * log2(e) into Q at store time
#define QSCALE (0.17677669529663687f * 1.4426950408889634f)

// Fragment-major layouts (produced by qkv_gemm, consumed by attn):
//  KF[head][t][f][lane][e]   : elem = K[32t + perm(lr) + 4f][lg*8+e],
//                              lane = lg*16+lr, perm(lr) = (lr>>2)*8 + (lr&3)
//  VF[head][t][half][lane][e]: elem = V[32t + lg*8 + e][16*half + lr]
// Strides (elems): head 32768, t 1024, f/half 512, lane 8.
// attn stages these LINEARLY to LDS (lane i <-> byte 16i): conflict-free b128.

// ---------------------------------------------------------------------------
// Kernel 1: QKV GEMM (reverted to R8/R9 -- measured good; R13's transposed
// epilogue caused 5x HBM write amplification, reverted).
// 128x128 block tile, BK=32, 8 K-steps, single-buffered; 128B/row swizzled
// LDS (16 KiB each); 3 blocks/CU, one round. s = by>>1 block-uniform.
// grid = (128, 6), block = 256.
// ---------------------------------------------------------------------------
__global__ __launch_bounds__(256, 3) void qkv_gemm(
    const float* __restrict__ x, const int* __restrict__ idx,
    const float* __restrict__ w_qkv,
    unsigned short* __restrict__ Qb, unsigned short* __restrict__ KF,
    unsigned short* __restrict__ VF)
{
  __shared__ __align__(16) unsigned short Asl[128*64];   // 16 KiB (128B/row)
  __shared__ __align__(16) unsigned short Bsl[128*64];   // 16 KiB
  const int tid = threadIdx.x;
  const int bx = blockIdx.x, by = blockIdx.y;
  const int m0 = bx << 7;
  const int bb = bx >> 5;           // batch (uniform per block)
  const int gg = (bx >> 3) & 3;     // group
  const int j0 = (bx & 31) << 7;    // permuted position base
  const int n0 = by << 7;

  int srow[2], brow[2], wb[2];
  #pragma unroll
  for (int it = 0; it < 2; ++it){
    int c = (it << 8) + tid;
    int row = c >> 2;
    int k8 = (c & 3) << 3;
    srow[it] = (bb << 12) + idx[j0 + row];
    brow[it] = n0 + row;
    wb[it] = ((row << 7) + (k8 << 1)) ^ ((row & 7) << 4);   // swizzled byte
  }

  #pragma unroll
  for (int it = 0; it < 2; ++it){
    int k8 = (((it << 8) + tid) & 3) << 3;
    const float* xs = x + srow[it]*256 + k8;
    const float* wsp = w_qkv + brow[it]*256 + k8;
    *(bf16x8*)((char*)Asl + wb[it]) = cvt8(*(const float4*)(xs), *(const float4*)(xs+4));
    *(bf16x8*)((char*)Bsl + wb[it]) = cvt8(*(const float4*)(wsp), *(const float4*)(wsp+4));
  }
  __syncthreads();

  const int lane = tid & 63;
  const int w = tid >> 6, wr = w >> 1, wc = w & 1;
  const int lr = lane & 15, lg = lane >> 4;
  const int ka = lg << 3;

  f32x4 acc[4][4];
  #pragma unroll
  for (int il = 0; il < 4; ++il)
    #pragma unroll
    for (int jl = 0; jl < 4; ++jl)
      acc[il][jl] = (f32x4){0.f,0.f,0.f,0.f};

  for (int st = 0; st < 8; ++st){
    float4 a0[2], a1[2], c0[2], c1[2];
    const bool pf = (st < 7);
    if (pf){
      int kb = (st + 1) << 5;
      #pragma unroll
      for (int it = 0; it < 2; ++it){
        int k8 = (((it << 8) + tid) & 3) << 3;
        const float* xs = x + srow[it]*256 + kb + k8;
        const float* wsp = w_qkv + brow[it]*256 + kb + k8;
        a0[it] = *(const float4*)(xs);  a1[it] = *(const float4*)(xs + 4);
        c0[it] = *(const float4*)(wsp); c1[it] = *(const float4*)(wsp + 4);
      }
    }

    bf16x8 af[4], bfr[4];
    #pragma unroll
    for (int il = 0; il < 4; ++il){
      int rowA = (wr << 6) + (il << 4) + lr;
      af[il] = *(const bf16x8*)((const char*)Asl + (((rowA << 7) + (ka << 1)) ^ ((rowA & 7) << 4)));
      int rowB = (wc << 6) + (il << 4) + lr;
      bfr[il] = *(const bf16x8*)((const char*)Bsl + (((rowB << 7) + (ka << 1)) ^ ((rowB & 7) << 4)));
    }
    __builtin_amdgcn_s_setprio(1);
    #pragma unroll
    for (int il = 0; il < 4; ++il)
      #pragma unroll
      for (int jl = 0; jl < 4; ++jl)
        acc[il][jl] = __builtin_amdgcn_mfma_f32_16x16x32_bf16(af[il], bfr[jl], acc[il][jl], 0, 0, 0);
    __builtin_amdgcn_s_setprio(0);

    __syncthreads();
    if (pf){
      #pragma unroll
      for (int it = 0; it < 2; ++it){
        *(bf16x8*)((char*)Asl + wb[it]) = cvt8(a0[it], a1[it]);
        *(bf16x8*)((char*)Bsl + wb[it]) = cvt8(c0[it], c1[it]);
      }
      __syncthreads();
    }
  }

  const int s = by >> 1;            // 0=Q 1=K 2=V
  const int hbase = ((bb << 2) + gg) << 3;
  #pragma unroll
  for (int il = 0; il < 4; ++il){
    int mr0 = m0 + (wr << 6) + (il << 4) + (lg << 2);
    int nl0 = mr0 & 1023;
    int t   = nl0 >> 5;
    #pragma unroll
    for (int jl = 0; jl < 4; ++jl){
      int ocol = ((by & 1) << 7) + (wc << 6) + (jl << 4) + lr;   // 0..255
      int h  = ocol >> 5, dd = ocol & 31;
      int head = hbase + h;
      if (s == 2){
        int m = nl0 & 31;
        int lane2 = ((m >> 3) << 4) + (dd & 15);
        int half = dd >> 4;
        ushort4 pk;
        pk.x = f2bf(acc[il][jl][0]); pk.y = f2bf(acc[il][jl][1]);
        pk.z = f2bf(acc[il][jl][2]); pk.w = f2bf(acc[il][jl][3]);
        *(ushort4*)(VF + head*32768 + t*1024 + half*512 + lane2*8 + (m & 7)) = pk;
      } else if (s == 1){
        int r0 = nl0 & 31;
        int f  = (r0 >> 2) & 1;
        unsigned short* dst = KF + head*32768 + t*1024 + f*512
                             + ((((dd >> 3) << 4) + ((r0 >> 3) << 2)) << 3) + (dd & 7);
        dst[0]  = f2bf(acc[il][jl][0]);
        dst[8]  = f2bf(acc[il][jl][1]);
        dst[16] = f2bf(acc[il][jl][2]);
        dst[24] = f2bf(acc[il][jl][3]);
      } else {
        unsigned short* dst = Qb + head*32768 + dd;
        #pragma unroll
        for (int q = 0; q < 4; ++q)
          dst[(nl0 + q) << 5] = f2bf(acc[il][jl][q] * QSCALE);
      }
    }
  }
}

// ---------------------------------------------------------------------------
// softmax over 16 scores/lane (no max tracking; see R6 analysis). 16 exp2 +
// pack. Denominator accumulated on the matrix pipe (ones-MFMA) by caller.
// ---------------------------------------------------------------------------
__device__ __forceinline__ void softmax16(
    const f32x4 s0, const f32x4 s1, const f32x4 s2, const f32x4 s3,
    bf16x8& pf0, bf16x8& pf1)
{
  float p0=__builtin_amdgcn_exp2f(s0[0]);  float p1=__builtin_amdgcn_exp2f(s0[1]);
  float p2=__builtin_amdgcn_exp2f(s0[2]);  float p3=__builtin_amdgcn_exp2f(s0[3]);
  float p4=__builtin_amdgcn_exp2f(s1[0]);  float p5=__builtin_amdgcn_exp2f(s1[1]);
  float p6=__builtin_amdgcn_exp2f(s1[2]);  float p7=__builtin_amdgcn_exp2f(s1[3]);
  float p8=__builtin_amdgcn_exp2f(s2[0]);  float p9=__builtin_amdgcn_exp2f(s2[1]);
  float p10=__builtin_amdgcn_exp2f(s2[2]); float p11=__builtin_amdgcn_exp2f(s2[3]);
  float p12=__builtin_amdgcn_exp2f(s3[0]); float p13=__builtin_amdgcn_exp2f(s3[1]);
  float p14=__builtin_amdgcn_exp2f(s3[2]); float p15=__builtin_amdgcn_exp2f(s3[3]);

  pf0[0]=(short)f2bf(p0);  pf0[1]=(short)f2bf(p1);
  pf0[2]=(short)f2bf(p2);  pf0[3]=(short)f2bf(p3);
  pf0[4]=(short)f2bf(p4);  pf0[5]=(short)f2bf(p5);
  pf0[6]=(short)f2bf(p6);  pf0[7]=(short)f2bf(p7);
  pf1[0]=(short)f2bf(p8);  pf1[1]=(short)f2bf(p9);
  pf1[2]=(short)f2bf(p10); pf1[3]=(short)f2bf(p11);
  pf1[4]=(short)f2bf(p12); pf1[5]=(short)f2bf(p13);
  pf1[6]=(short)f2bf(p14); pf1[7]=(short)f2bf(p15);
}

// ---------------------------------------------------------------------------
// Kernel 2: attention (R9 structure + XCD-aware blockIdx swizzle).
// 4 waves x 64 q (4 q-groups), dbuf 128-m tiles, reg-staged async-split.
// Swizzle b = (bid&7)*64 + bid>>3 (bijective, 512 = 8*64): all 4 q-blocks
// of a head land on ONE XCD -> its 64KB K/V is fetched into one L2, not 4.
// grid = 512, block = 256.
// ---------------------------------------------------------------------------
__global__ __launch_bounds__(256, 2) void attn_kernel(
    const unsigned short* __restrict__ Qb, const unsigned short* __restrict__ KF,
    const unsigned short* __restrict__ VF, unsigned short* __restrict__ OB)
{
  __shared__ __align__(16) char lds[32768];   // [buf 2][K 8KB | V 8KB]
  const int tid  = threadIdx.x;
  const int bid  = blockIdx.x;
  const int b    = ((bid & 7) << 6) + (bid >> 3);   // XCD swizzle (bijective)
  const int head = b >> 2;
  const int qblk = b & 3;
  const int lane = tid & 63;
  const int w  = tid >> 6;
  const int lr = lane & 15, lg = lane >> 4;
  const int q0 = qblk * 256 + w * 64;

  const unsigned short* kf = KF + head*32768;
  const unsigned short* vf = VF + head*32768;
  const unsigned short* qbase = Qb + head*32768;

  {
    bf16x8 k0 = *(const bf16x8*)(kf + tid*8);
    bf16x8 k1 = *(const bf16x8*)(kf + 2048 + tid*8);
    bf16x8 v0 = *(const bf16x8*)(vf + tid*8);
    bf16x8 v1 = *(const bf16x8*)(vf + 2048 + tid*8);
    *(bf16x8*)(lds + tid*16)          = k0;
    *(bf16x8*)(lds + 4096 + tid*16)   = k1;
    *(bf16x8*)(lds + 8192 + tid*16)   = v0;
    *(bf16x8*)(lds + 12288 + tid*16)  = v1;
  }

  bf16x8 qf[4];
  #pragma unroll
  for (int g = 0; g < 4; ++g)
    qf[g] = *(const bf16x8*)(qbase + (q0 + g*16 + lr)*32 + (lg << 3));

  const short one_bf = (short)0x3F80;   // bf16 1.0
  bf16x8 onesf = {one_bf,one_bf,one_bf,one_bf,one_bf,one_bf,one_bf,one_bf};

  f32x4 o0[4], o1[4], ls[4];
  #pragma unroll
  for (int g = 0; g < 4; ++g){
    o0[g] = (f32x4){0.f,0.f,0.f,0.f};
    o1[g] = (f32x4){0.f,0.f,0.f,0.f};
    ls[g] = (f32x4){0.f,0.f,0.f,0.f};
  }
  const f32x4 zz={0.f,0.f,0.f,0.f};

  __syncthreads();
  int cur = 0;
  for (int it = 0; it < 8; ++it){
    bf16x8 kr0, kr1, vr0, vr1;
    const bool pfch = (it < 7);
    if (pfch){
      const unsigned short* kg = kf + (it+1)*4096 + tid*8;
      const unsigned short* vg = vf + (it+1)*4096 + tid*8;
      kr0 = *(const bf16x8*)(kg);
      kr1 = *(const bf16x8*)(kg + 2048);
      vr0 = *(const bf16x8*)(vg);
      vr1 = *(const bf16x8*)(vg + 2048);
    }

    const char* KL = lds + cur*16384 + lane*16;
    const char* VL = KL + 8192;
    #pragma unroll
    for (int hh = 0; hh < 2; ++hh){
      const char* kp_ = KL + hh*4096;
      const char* vp_ = VL + hh*4096;
      bf16x8 kA0 = *(const bf16x8*)(kp_);
      bf16x8 kB0 = *(const bf16x8*)(kp_ + 1024);
      bf16x8 kA1 = *(const bf16x8*)(kp_ + 2048);
      bf16x8 kB1 = *(const bf16x8*)(kp_ + 3072);
      bf16x8 v00 = *(const bf16x8*)(vp_);
      bf16x8 v01 = *(const bf16x8*)(vp_ + 1024);
      bf16x8 v10 = *(const bf16x8*)(vp_ + 2048);
      bf16x8 v11 = *(const bf16x8*)(vp_ + 3072);

      // 4-group pipeline: QK(g+1) on matrix pipe overlaps softmax(g) VALU.
      __builtin_amdgcn_s_setprio(1);
      f32x4 sA0 = __builtin_amdgcn_mfma_f32_16x16x32_bf16(kA0, qf[0], zz, 0, 0, 0);
      f32x4 sB0 = __builtin_amdgcn_mfma_f32_16x16x32_bf16(kB0, qf[0], zz, 0, 0, 0);
      f32x4 sA1 = __builtin_amdgcn_mfma_f32_16x16x32_bf16(kA1, qf[0], zz, 0, 0, 0);
      f32x4 sB1 = __builtin_amdgcn_mfma_f32_16x16x32_bf16(kB1, qf[0], zz, 0, 0, 0);
      __builtin_amdgcn_s_setprio(0);

      #pragma unroll
      for (int g = 0; g < 4; ++g){
        f32x4 nA0, nB0, nA1, nB1;
        if (g < 3){
          __builtin_amdgcn_s_setprio(1);
          nA0 = __builtin_amdgcn_mfma_f32_16x16x32_bf16(kA0, qf[g+1], zz, 0, 0, 0);
          nB0 = __builtin_amdgcn_mfma_f32_16x16x32_bf16(kB0, qf[g+1], zz, 0, 0, 0);
          nA1 = __builtin_amdgcn_mfma_f32_16x16x32_bf16(kA1, qf[g+1], zz, 0, 0, 0);
          nB1 = __builtin_amdgcn_mfma_f32_16x16x32_bf16(kB1, qf[g+1], zz, 0, 0, 0);
          __builtin_amdgcn_s_setprio(0);
        }
        bf16x8 pf0, pf1;
        softmax16(sA0, sB0, sA1, sB1, pf0, pf1);   // VALU; overlaps QK(g+1)
        __builtin_amdgcn_s_setprio(1);
        o0[g] = __builtin_amdgcn_mfma_f32_16x16x32_bf16(pf0, v00, o0[g], 0, 0, 0);
        o1[g] = __builtin_amdgcn_mfma_f32_16x16x32_bf16(pf0, v01, o1[g], 0, 0, 0);
        o0[g] = __builtin_amdgcn_mfma_f32_16x16x32_bf16(pf1, v10, o0[g], 0, 0, 0);
        o1[g] = __builtin_amdgcn_mfma_f32_16x16x32_bf16(pf1, v11, o1[g], 0, 0, 0);
        ls[g] = __builtin_amdgcn_mfma_f32_16x16x32_bf16(pf0, onesf, ls[g], 0, 0, 0);
        ls[g] = __builtin_amdgcn_mfma_f32_16x16x32_bf16(pf1, onesf, ls[g], 0, 0, 0);
        __builtin_amdgcn_s_setprio(0);
        if (g < 3){ sA0 = nA0; sB0 = nB0; sA1 = nA1; sB1 = nB1; }
      }
    }

    if (pfch){
      char* db = lds + (cur^1)*16384;
      *(bf16x8*)(db + tid*16)          = kr0;
      *(bf16x8*)(db + 4096 + tid*16)   = kr1;
      *(bf16x8*)(db + 8192 + tid*16)   = vr0;
      *(bf16x8*)(db + 12288 + tid*16)  = vr1;
    }
    __syncthreads();
    cur ^= 1;
  }

  // epilogue: ls[g][q] holds the full row sum for row q0+g*16+lg*4+q.
  const int bI = head >> 5, gI = (head >> 3) & 3, hI = head & 7;
  unsigned short* obase = OB + (bI*4096 + gI*1024 + q0)*256 + hI*32;
  #pragma unroll
  for (int g = 0; g < 4; ++g){
    #pragma unroll
    for (int q = 0; q < 4; ++q){
      float iv = 1.0f / ls[g][q];
      int r = (g << 4) + (lg << 2) + q;
      obase[r*256 + lr]      = f2bf(o0[g][q] * iv);
      obase[r*256 + 16 + lr] = f2bf(o1[g][q] * iv);
    }
  }
}

// ---------------------------------------------------------------------------
// Kernel 3: projection GEMM (unchanged). A = bf16 OB (cvt-free linear
// staging), B^T = w_proj. out[b, idx[j], :] = row j + bias.
// grid = (256, 2), block = 256.
// ---------------------------------------------------------------------------
__global__ __launch_bounds__(256) void proj_gemm(
    const unsigned short* __restrict__ OB, const float* __restrict__ w_proj,
    const float* __restrict__ b_proj, const int* __restrict__ idx,
    float* __restrict__ out)
{
  __shared__ unsigned short Alds[64*256];
  __shared__ unsigned short Blds[64*256];
  const int tid = threadIdx.x;
  const int m0 = blockIdx.x << 6;
  const int bb = m0 >> 12;

  #pragma unroll
  for (int it = 0; it < 8; ++it){
    int c = (it << 8) + tid;
    int row = c >> 5;
    int k8 = (c & 31) << 3;
    int byt = ((row << 9) + (k8 << 1)) ^ ((row & 7) << 4);
    *(bf16x8*)((char*)Alds + byt) = *(const bf16x8*)(OB + (m0+row)*256 + k8);
  }

  const int w  = tid >> 6, lane = tid & 63;
  const int lr = lane & 15, lg = lane >> 4;
  const int wr = w >> 1,  wc = w & 1;

  for (int nt = 0; nt < 2; ++nt){
    const int n0 = blockIdx.y * 128 + nt * 64;
    __syncthreads();
    #pragma unroll
    for (int it = 0; it < 8; ++it){
      int c = (it << 8) + tid;
      int row = c >> 5;
      int k8 = (c & 31) << 3;
      const float4 f0 = *(const float4*)(w_proj + (n0+row)*256 + k8);
      const float4 f1 = *(const float4*)(w_proj + (n0+row)*256 + k8 + 4);
      bf16x8 v;
      v[0]=(short)f2bf(f0.x); v[1]=(short)f2bf(f0.y);
      v[2]=(short)f2bf(f0.z); v[3]=(short)f2bf(f0.w);
      v[4]=(short)f2bf(f1.x); v[5]=(short)f2bf(f1.y);
      v[6]=(short)f2bf(f1.z); v[7]=(short)f2bf(f1.w);
      int byt = ((row << 9) + (k8 << 1)) ^ ((row & 7) << 4);
      *(bf16x8*)((char*)Blds + byt) = v;
    }
    __syncthreads();

    f32x4 acc[2][2];
    #pragma unroll
    for (int i=0;i<2;++i)
      #pragma unroll
      for (int j=0;j<2;++j)
        acc[i][j] = (f32x4){0.f,0.f,0.f,0.f};

    #pragma unroll
    for (int ks = 0; ks < 8; ++ks){
      bf16x8 af[2], bfr[2];
      int ka = (ks << 5) + (lg << 3);
      #pragma unroll
      for (int i=0;i<2;++i){
        int rowA = (wr << 5) + (i << 4) + lr;
        int bytA = ((rowA << 9) + (ka << 1)) ^ ((rowA & 7) << 4);
        af[i] = *(const bf16x8*)((const char*)Alds + bytA);
        int rowB = (wc << 5) + (i << 4) + lr;
        int bytB = ((rowB << 9) + (ka << 1)) ^ ((rowB & 7) << 4);
        bfr[i] = *(const bf16x8*)((const char*)Blds + bytB);
      }
      #pragma unroll
      for (int i=0;i<2;++i)
        #pragma unroll
        for (int j=0;j<2;++j)
          acc[i][j] = __builtin_amdgcn_mfma_f32_16x16x32_bf16(af[i], bfr[j], acc[i][j], 0, 0, 0);
    }

    #pragma unroll
    for (int i=0;i<2;++i){
      int mr0 = m0 + (wr << 5) + (i << 4) + (lg << 2);
      int rd[4];
      #pragma unroll
      for (int q=0;q<4;++q)
        rd[q] = (bb << 12) + idx[(mr0 + q) & 4095];   // inverse perm as scatter
      #pragma unroll
      for (int j=0;j<2;++j){
        int o = n0 + (wc << 5) + (j << 4) + lr;
        float bias = b_proj[o];
        #pragma unroll
        for (int q=0;q<4;++q)
          out[rd[q]*256 + o] = acc[i][j][q] + bias;
      }
    }
  }
}

// ---------------------------------------------------------------------------
extern "C" void kernel_launch(void* const* d_in, const int* in_sizes, int n_in,
                              void* d_out, int out_size, void* d_ws, size_t ws_size,
                              hipStream_t stream)
{
  const float* x      = (const float*)d_in[0];
  const int*   idx    = (const int*)  d_in[1];
  const float* w_qkv  = (const float*)d_in[2];
  const float* w_proj = (const float*)d_in[3];
  const float* b_proj = (const float*)d_in[4];
  float* out = (float*)d_out;

  char* ws = (char*)d_ws;
  unsigned short* Qb = (unsigned short*)(ws);                  // 8 MiB
  unsigned short* KF = (unsigned short*)(ws + (8u  << 20));    // 8 MiB (frag-major)
  unsigned short* VF = (unsigned short*)(ws + (16u << 20));    // 8 MiB (frag-major)
  unsigned short* OB = (unsigned short*)(ws + (24u << 20));    // 8 MiB bf16 O rows

  qkv_gemm<<<dim3(128, 6), 256, 0, stream>>>(x, idx, w_qkv, Qb, KF, VF);
  attn_kernel<<<dim3(512), 256, 0, stream>>>(Qb, KF, VF, OB);
  proj_gemm<<<dim3(256, 2), 256, 0, stream>>>(OB, w_proj, b_proj, idx, out);
}